// Round 7
// baseline (184.303 us; speedup 1.0000x reference)
//
#include <hip/hip_runtime.h>
#include <hip/hip_bf16.h>
#include <cstdint>
#include <cstddef>

constexpr int B_ = 2;
constexpr int HH = 192, WW = 192, HW_ = HH * WW;
constexpr int HP = 194, WPAD = 200;   // padded dims

typedef short bf16x8 __attribute__((ext_vector_type(8)));
typedef short s16x4  __attribute__((ext_vector_type(4)));
typedef float f32x4  __attribute__((ext_vector_type(4)));

typedef __attribute__((address_space(1))) const void GLB;
typedef __attribute__((address_space(3))) void LDS;

__device__ __forceinline__ float bf2f(unsigned short h) {
  union { unsigned u; float f; } v; v.u = (unsigned)h << 16; return v.f;
}
__device__ __forceinline__ unsigned short f2bf(float f) {
  union { float f; unsigned u; } v; v.f = f;
  unsigned u = v.u;
  u += 0x7fffu + ((u >> 16) & 1u);
  return (unsigned short)(u >> 16);
}
__device__ __forceinline__ float leaky(float v) { return fmaxf(v, 0.1f * v); }

// ---------------------------------------------------------------------------
// NCHW f32 -> NHWC bf16 (padded interior of [HP][WPAD]).
// ---------------------------------------------------------------------------
template<int DSTC, bool PAD>
__global__ __launch_bounds__(256) void to_nhwc(const float* __restrict__ src,
                                               unsigned short* __restrict__ dst,
                                               int coff)
{
  __shared__ float tile[16][65];
  int t = threadIdx.x;
  int xc = blockIdx.x * 16;
  int y = blockIdx.y % HH, b = blockIdx.y / HH;
  #pragma unroll
  for (int cp = 0; cp < 4; ++cp) {
    int c = cp * 16 + (t >> 4);
    tile[t & 15][c] = src[((size_t)(b * 64 + c) * HH + y) * WW + xc + (t & 15)];
  }
  __syncthreads();
  int x = t >> 4, c4 = (t & 15) * 4;
  s16x4 s;
  #pragma unroll
  for (int j = 0; j < 4; ++j) s[j] = (short)f2bf(tile[x][c4 + j]);
  size_t pbase = PAD
      ? ((size_t)(b * HP + y + 1) * WPAD + xc + x + 1) * DSTC + coff + c4
      : ((size_t)(b * HH + y) * WW + xc + x) * DSTC + coff + c4;
  *(s16x4*)&dst[pbase] = s;
}

// ---------------------------------------------------------------------------
// prev NCHW f32 -> group-planar bf16 [b][8][192][192][8]  (for deform gathers)
// ---------------------------------------------------------------------------
__global__ __launch_bounds__(256) void to_gp(const float* __restrict__ src,
                                             unsigned short* __restrict__ gp)
{
  int tid = blockIdx.x * 256 + threadIdx.x;     // 589824 = 2304 * 256 exact
  int x = tid % WW;
  int y = (tid / WW) % HH;
  int g = (tid / HW_) % 8;
  int b = tid / (8 * HW_);
  const float* sp = src + ((size_t)(b * 64 + g * 8) * HH + y) * WW + x;
  bf16x8 v;
  #pragma unroll
  for (int c = 0; c < 8; ++c) v[c] = (short)f2bf(sp[(size_t)c * HW_]);
  *(bf16x8*)&gp[(size_t)tid * 8] = v;
}

// ---------------------------------------------------------------------------
// Weight transform: (O, CI, 3, 3) f32 -> tap-major [k][o][ci] bf16.
// K1/K3/K4 images get the LDS XOR bank-swizzle; deform (w_dcn) stays plain.
// ---------------------------------------------------------------------------
__global__ __launch_bounds__(256) void wxform(
    const float* __restrict__ w_off, const float* __restrict__ w_dcn,
    const float* __restrict__ w_r1,  const float* __restrict__ w_r2,
    unsigned short* __restrict__ wOffB, unsigned short* __restrict__ wDcnB,
    unsigned short* __restrict__ wR1B,  unsigned short* __restrict__ wR2B)
{
  int tid = blockIdx.x * 256 + threadIdx.x;   // 230400 total
  const float* src; unsigned short* dst; int CI, CO, idx; bool dosw = true;
  if (tid < 82944)            { src = w_off; dst = wOffB; CI = 64;  CO = 144; idx = tid; }
  else if (tid < 119808)      { src = w_dcn; dst = wDcnB; CI = 64;  CO = 64;  idx = tid - 82944; dosw = false; }
  else if (tid < 193536)      { src = w_r1;  dst = wR1B;  CI = 128; CO = 64;  idx = tid - 119808; }
  else                        { src = w_r2;  dst = wR2B;  CI = 64;  CO = 64;  idx = tid - 193536; }
  int ci = idx % CI;
  int k  = (idx / CI) % 9;
  int o  = idx / (CI * 9);
  int pci = dosw ? (((((ci >> 3) ^ (o & 7))) << 3) | (ci & 7)) : ci;
  dst[((size_t)k * CO + o) * CI + pci] = f2bf(src[((size_t)o * CI + ci) * 9 + k]);
}

// ---------------------------------------------------------------------------
// MFMA implicit-GEMM 3x3 conv. Pixels staged once in LDS; per-tap weights
// staged in LDS via global_load_lds (DBUF: double-buffered, 1 barrier/tap).
// OUTMODE 0: bf16 NCHW (K1) | 1: bf16 NHWC padded (K3) | 2: f32 NCHW + resid (K4)
// launch_bounds(256,4): cap 128 VGPR — 48-VGPR auto-target strangled scheduling.
// ---------------------------------------------------------------------------
template<int CIN, int COUT, int NF, bool LEAKY_, int OUTMODE, bool DBUF>
__global__ __launch_bounds__(256, 4) void conv_mfma(
    const unsigned short* __restrict__ inT,   // [b][HP][WPAD][CIN] bf16
    const unsigned short* __restrict__ wS,    // [9][COUT][CIN] bf16, swizzled image
    const float* __restrict__ bias,
    const unsigned short* __restrict__ resid,
    void* __restrict__ outp)
{
  constexpr int CPP  = CIN / 8;          // 16B chunks per pixel
  constexpr int TPX  = 72;
  constexpr int NCH  = TPX * CPP;        // chunks per staged row
  constexpr int RPR  = NCH / 64;         // wave-regions per row
  constexpr int NREG = 3 * RPR;
  constexpr int WSZ  = COUT * CIN;       // weight elems per tap
  constexpr int WCH  = WSZ / 8;          // 16B chunks per tap
  __shared__ __align__(16) unsigned short tile[3 * TPX * CIN];
  __shared__ __align__(16) unsigned short wlds[(DBUF ? 2 : 1) * WSZ];

  const int t = threadIdx.x;
  const int l = t & 63, wv = t >> 6;
  const int lr = l & 15, lq = l >> 4, lk = lq * 8;

  // XCD-aware bijective swizzle (1152 % 8 == 0)
  constexpr int NWG = 3 * 384;
  int lin = blockIdx.x + 3 * blockIdx.y;
  int swz = (lin & 7) * (NWG / 8) + (lin >> 3);
  int xq = swz % 3, yy = swz / 3;
  int y = yy % HH, b = yy / HH;
  int x0 = xq * 64;

  // ---- stage 3 pixel rows (72 px each, swizzled) + weight tap 0
  {
    const unsigned short* base = inT + ((size_t)(b * HP + y) * WPAD + x0) * CIN;
    for (int r = wv; r < NREG; r += 4) {
      int row = r / RPR;
      int rr  = r % RPR;
      int d   = rr * 64 + l;
      int p   = d / CPP;
      int cj  = d % CPP;
      int sc  = p * CPP + (cj ^ (p & (CPP - 1)));
      const unsigned short* src = base + (size_t)row * WPAD * CIN + (size_t)sc * 8;
      unsigned short* dst = &tile[(size_t)(row * NCH + rr * 64) * 8];
      __builtin_amdgcn_global_load_lds((GLB*)src, (LDS*)dst, 16, 0, 0);
    }
  }
  {
    const unsigned short* srcb = wS;                 // tap 0
    for (int r = t; r < WCH; r += 256)
      __builtin_amdgcn_global_load_lds((GLB*)(srcb + (size_t)r * 8),
                                       (LDS*)(&wlds[(size_t)r * 8]), 16, 0, 0);
  }
  __syncthreads();

  f32x4 acc[NF];
  #pragma unroll
  for (int f = 0; f < NF; ++f) acc[f] = f32x4{0.f, 0.f, 0.f, 0.f};

  #pragma unroll
  for (int k = 0; k < 9; ++k) {
    const int ky = k / 3, kx = k % 3;
    if (DBUF && k < 8) {
      const unsigned short* srcb = wS + (size_t)(k + 1) * WSZ;
      unsigned short* db = &wlds[(size_t)((k + 1) & 1) * WSZ];
      for (int r = t; r < WCH; r += 256)
        __builtin_amdgcn_global_load_lds((GLB*)(srcb + (size_t)r * 8),
                                         (LDS*)(db + (size_t)r * 8), 16, 0, 0);
    }
    // ---- compute tap k
    {
      const unsigned short* wb = &wlds[DBUF ? (size_t)(k & 1) * WSZ : 0];
      const int px = wv * 16 + lr + kx;
      #pragma unroll
      for (int c = 0; c < CIN; c += 32) {
        int cj = (c + lk) >> 3;
        bf16x8 pf = *(const bf16x8*)
            &tile[(size_t)(ky * NCH + px * CPP + (cj ^ (px & (CPP - 1)))) * 8];
        #pragma unroll
        for (int f = 0; f < NF; ++f) {
          int co = f * 16 + lr;
          bf16x8 wf = *(const bf16x8*)&wb[(size_t)co * CIN + ((cj ^ (co & 7)) << 3)];
          if (OUTMODE == 0)
            acc[f] = __builtin_amdgcn_mfma_f32_16x16x32_bf16(pf, wf, acc[f], 0, 0, 0);
          else
            acc[f] = __builtin_amdgcn_mfma_f32_16x16x32_bf16(wf, pf, acc[f], 0, 0, 0);
        }
      }
    }
    if (DBUF) {
      __syncthreads();
    } else if (k < 8) {
      __syncthreads();                       // all reads of wlds done
      const unsigned short* srcb = wS + (size_t)(k + 1) * WSZ;
      for (int r = t; r < WCH; r += 256)
        __builtin_amdgcn_global_load_lds((GLB*)(srcb + (size_t)r * 8),
                                         (LDS*)(&wlds[(size_t)r * 8]), 16, 0, 0);
      __syncthreads();                       // staging complete
    }
  }

  if (OUTMODE == 0) {
    int xs = x0 + wv * 16 + lq * 4;
    #pragma unroll
    for (int f = 0; f < NF; ++f) {
      int co = f * 16 + lr;
      float bv = bias[co];
      s16x4 s;
      #pragma unroll
      for (int j = 0; j < 4; ++j) {
        float v = acc[f][j] + bv;
        if (LEAKY_) v = leaky(v);
        s[j] = (short)f2bf(v);
      }
      *(s16x4*)((unsigned short*)outp + ((size_t)(b * COUT + co) * HH + y) * WW + xs) = s;
    }
  } else if (OUTMODE == 1) {
    int x = x0 + wv * 16 + lr;
    #pragma unroll
    for (int f = 0; f < NF; ++f) {
      int co = f * 16 + lq * 4;
      f32x4 bv = *(const f32x4*)&bias[co];
      s16x4 s;
      #pragma unroll
      for (int j = 0; j < 4; ++j) {
        float v = acc[f][j] + bv[j];
        if (LEAKY_) v = leaky(v);
        s[j] = (short)f2bf(v);
      }
      *(s16x4*)((unsigned short*)outp + ((size_t)(b * HP + y + 1) * WPAD + x + 1) * 64 + co) = s;
    }
  } else {
    int x = x0 + wv * 16 + lr;
    const unsigned short* rbase = resid + ((size_t)(b * HP + y + 1) * WPAD + x + 1) * 128;
    float* ob = (float*)outp + (size_t)b * 64 * HW_ + (size_t)y * WW + x;
    #pragma unroll
    for (int f = 0; f < NF; ++f) {
      int cob = f * 16 + lq * 4;
      f32x4 bv = *(const f32x4*)&bias[cob];
      s16x4 rv = *(const s16x4*)&rbase[cob];
      #pragma unroll
      for (int j = 0; j < 4; ++j) {
        float v = acc[f][j] + bv[j];
        if (LEAKY_) v = leaky(v);
        v += bf2f((unsigned short)rv[j]);
        ob[(size_t)(cob + j) * HW_] = v;
      }
    }
  }
}

// ---------------------------------------------------------------------------
// Deformable conv, barrier-free wave-private design, paired-x gathers.
// launch_bounds(256,3): cap ~170 VGPR so the offset preload + GA/GB pipeline
// actually stay in registers (at default bounds the compiler serialized it).
// ---------------------------------------------------------------------------
struct GT {
  bf16x8 p0l[2], p0h[2], p1l[2], p1h[2];   // rows y0/y1, halves ixb/ixb+1
  float  cl0[2], ch0[2], cl1[2], ch1[2];
};

template<int K>
__device__ __forceinline__ void dcn_issue(
    const unsigned short* __restrict__ gp, int b, int y, int xpix, int lq,
    const unsigned (&dd)[2][9], GT& G)
{
  constexpr int ky = K / 3, kx = K % 3;
  #pragma unroll
  for (int gi = 0; gi < 2; ++gi) {
    int g = lq + gi * 4;
    float dyv = bf2f((unsigned short)(dd[gi][K] & 0xffffu));
    float dxv = bf2f((unsigned short)(dd[gi][K] >> 16));
    float py = (float)(y - 1 + ky) + dyv;
    float px = (float)(xpix - 1 + kx) + dxv;
    float fy0 = floorf(py), fx0 = floorf(px);
    float wy1 = py - fy0, wx1 = px - fx0;
    float wy0 = 1.f - wy1, wx0 = 1.f - wx1;
    bool vy0 = (fy0 >= 0.f)  && (fy0 <= 191.f);
    bool vy1 = (fy0 >= -1.f) && (fy0 <= 190.f);
    bool vx0 = (fx0 >= 0.f)  && (fx0 <= 191.f);
    bool vx1 = (fx0 >= -1.f) && (fx0 <= 190.f);
    float c00 = (vy0 && vx0) ? wy0 * wx0 : 0.f;
    float c01 = (vy0 && vx1) ? wy0 * wx1 : 0.f;
    float c10 = (vy1 && vx0) ? wy1 * wx0 : 0.f;
    float c11 = (vy1 && vx1) ? wy1 * wx1 : 0.f;
    // remap corner coefficients onto the two 16B halves of a paired load at
    // ixb = clamp(fx0, 0, 190). x0 lands in hi half only when fx0 > 190;
    // x1 lands in lo half only when fx0 < 0. Verified over all clamp cases.
    bool x0hi = (fx0 > 190.f);
    bool x1lo = (fx0 < 0.f);
    G.cl0[gi] = (x0hi ? 0.f : c00) + (x1lo ? c01 : 0.f);
    G.ch0[gi] = (x0hi ? c00 : 0.f) + (x1lo ? 0.f : c01);
    G.cl1[gi] = (x0hi ? 0.f : c10) + (x1lo ? c11 : 0.f);
    G.ch1[gi] = (x0hi ? c10 : 0.f) + (x1lo ? 0.f : c11);
    int iy0 = (int)fminf(fmaxf(fy0, 0.f), 191.f);
    int iy1 = (int)fminf(fmaxf(fy0 + 1.f, 0.f), 191.f);
    int ixb = (int)fminf(fmaxf(fx0, 0.f), 190.f);
    const unsigned short* bb = gp + (size_t)(b * 8 + g) * (HW_ * 8);
    const unsigned short* r0 = bb + ((size_t)(iy0 * WW) + ixb) * 8;
    const unsigned short* r1 = bb + ((size_t)(iy1 * WW) + ixb) * 8;
    G.p0l[gi] = *(const bf16x8*)r0;
    G.p0h[gi] = *(const bf16x8*)(r0 + 8);
    G.p1l[gi] = *(const bf16x8*)r1;
    G.p1h[gi] = *(const bf16x8*)(r1 + 8);
  }
}

template<int K>
__device__ __forceinline__ void dcn_consume(
    const unsigned short* __restrict__ wD, int lr, int lq,
    GT& G, f32x4 (&acc)[4])
{
  bf16x8 pf0, pf1;
  #pragma unroll
  for (int gi = 0; gi < 2; ++gi) {
    bf16x8 sv;
    #pragma unroll
    for (int j = 0; j < 8; ++j) {
      float s = bf2f((unsigned short)G.p0l[gi][j]) * G.cl0[gi]
              + bf2f((unsigned short)G.p0h[gi][j]) * G.ch0[gi]
              + bf2f((unsigned short)G.p1l[gi][j]) * G.cl1[gi]
              + bf2f((unsigned short)G.p1h[gi][j]) * G.ch1[gi];
      sv[j] = (short)f2bf(s);
    }
    if (gi == 0) pf0 = sv; else pf1 = sv;
  }
  #pragma unroll
  for (int f = 0; f < 4; ++f) {
    bf16x8 wf = *(const bf16x8*)&wD[((size_t)K * 64 + f * 16 + lr) * 64 + lq * 8];
    acc[f] = __builtin_amdgcn_mfma_f32_16x16x32_bf16(wf, pf0, acc[f], 0, 0, 0);
  }
  #pragma unroll
  for (int f = 0; f < 4; ++f) {
    bf16x8 wf = *(const bf16x8*)&wD[((size_t)K * 64 + f * 16 + lr) * 64 + 32 + lq * 8];
    acc[f] = __builtin_amdgcn_mfma_f32_16x16x32_bf16(wf, pf1, acc[f], 0, 0, 0);
  }
}

__global__ __launch_bounds__(256, 3) void deform_mfma(
    const unsigned short* __restrict__ gp,    // [b][8][192][192][8] bf16
    const unsigned short* __restrict__ off,   // [b][144][192][192] bf16
    const unsigned short* __restrict__ wD,    // [9][64][64] bf16 plain
    const float* __restrict__ bias,
    unsigned short* __restrict__ concatT)     // [b][HP][WPAD][128], writes ch0-63
{
  const int t = threadIdx.x;
  const int l = t & 63, wv = t >> 6;
  const int lr = l & 15, lq = l >> 4;

  int lin = blockIdx.x;                       // 1152 blocks
  int swz = (lin & 7) * 144 + (lin >> 3);     // XCD-aware bijective
  int xq = swz % 3, yy = swz / 3;
  int y = yy % HH, b = yy / HH;
  int xpix = xq * 64 + wv * 16 + lr;          // this lane's pixel

  // ---- preload all offsets, packed (dy | dx<<16) per (group, tap): 18 dwords
  unsigned dd[2][9];
  #pragma unroll
  for (int gi = 0; gi < 2; ++gi) {
    int g = lq + gi * 4;
    const unsigned short* op = off + ((size_t)(b * 144 + g * 18) * HH + y) * WW + xpix;
    #pragma unroll
    for (int k = 0; k < 9; ++k) {
      unsigned dyv = op[(size_t)(2 * k) * HW_];
      unsigned dxv = op[(size_t)(2 * k + 1) * HW_];
      dd[gi][k] = dyv | (dxv << 16);
    }
  }

  f32x4 acc[4];
  #pragma unroll
  for (int f = 0; f < 4; ++f) acc[f] = f32x4{0.f, 0.f, 0.f, 0.f};

  GT GA, GB;
  dcn_issue<0>(gp, b, y, xpix, lq, dd, GA);
  dcn_issue<1>(gp, b, y, xpix, lq, dd, GB);
  dcn_consume<0>(wD, lr, lq, GA, acc);
  dcn_issue<2>(gp, b, y, xpix, lq, dd, GA);
  dcn_consume<1>(wD, lr, lq, GB, acc);
  dcn_issue<3>(gp, b, y, xpix, lq, dd, GB);
  dcn_consume<2>(wD, lr, lq, GA, acc);
  dcn_issue<4>(gp, b, y, xpix, lq, dd, GA);
  dcn_consume<3>(wD, lr, lq, GB, acc);
  dcn_issue<5>(gp, b, y, xpix, lq, dd, GB);
  dcn_consume<4>(wD, lr, lq, GA, acc);
  dcn_issue<6>(gp, b, y, xpix, lq, dd, GA);
  dcn_consume<5>(wD, lr, lq, GB, acc);
  dcn_issue<7>(gp, b, y, xpix, lq, dd, GB);
  dcn_consume<6>(wD, lr, lq, GA, acc);
  dcn_issue<8>(gp, b, y, xpix, lq, dd, GA);
  dcn_consume<7>(wD, lr, lq, GB, acc);
  dcn_consume<8>(wD, lr, lq, GA, acc);

  // epilogue: NHWC bf16 into concat channels [0,64). C: col=pixel=lr, row=lq*4+j
  unsigned short* outc = concatT + (size_t)b * HP * WPAD * 128;
  #pragma unroll
  for (int f = 0; f < 4; ++f) {
    int co = f * 16 + lq * 4;
    f32x4 bv = *(const f32x4*)&bias[co];
    s16x4 s;
    #pragma unroll
    for (int j = 0; j < 4; ++j) s[j] = (short)f2bf(acc[f][j] + bv[j]);
    *(s16x4*)&outc[((size_t)(y + 1) * WPAD + xpix + 1) * 128 + co] = s;
  }
}

// ---------------------------------------------------------------------------
extern "C" void kernel_launch(void* const* d_in, const int* in_sizes, int n_in,
                              void* d_out, int out_size, void* d_ws, size_t ws_size,
                              hipStream_t stream)
{
  const float* prev  = (const float*)d_in[0];
  const float* offin = (const float*)d_in[1];
  const float* w_off = (const float*)d_in[2];
  const float* b_off = (const float*)d_in[3];
  const float* w_dcn = (const float*)d_in[4];
  const float* b_dcn = (const float*)d_in[5];
  const float* w_r1  = (const float*)d_in[6];
  const float* b_r1  = (const float*)d_in[7];
  const float* w_r2  = (const float*)d_in[8];
  const float* b_r2  = (const float*)d_in[9];
  float* out = (float*)d_out;

  char* p = (char*)d_ws;
  unsigned short* offs_t   = (unsigned short*)p; p += (size_t)B_ * HP * WPAD * 64 * 2;   //  9.93 MB
  unsigned short* concat_t = (unsigned short*)p; p += (size_t)B_ * HP * WPAD * 128 * 2;  // 19.87 MB
  unsigned short* r1_t     = (unsigned short*)p; p += (size_t)B_ * HP * WPAD * 64 * 2;   //  9.93 MB
  unsigned short* offf     = (unsigned short*)p; p += (size_t)B_ * 144 * HW_ * 2;        // 21.23 MB
  unsigned short* wOffB    = (unsigned short*)p; p += 144 * 576 * 2;
  unsigned short* wDcnB    = (unsigned short*)p; p += 64 * 576 * 2;
  unsigned short* wR1B     = (unsigned short*)p; p += 64 * 1152 * 2;
  unsigned short* wR2B     = (unsigned short*)p; p += 64 * 576 * 2;                      // total ~61.4 MB
  // gp (group-planar prev, 9.44 MB) aliases offs_t (9.93 MB): offs_t is dead
  // after K1, and to_gp runs after K1 on the same stream.
  unsigned short* gp = offs_t;

  // Zero padded NHWC buffers (contiguous) so pad borders are 0.
  hipMemsetAsync(offs_t, 0, (size_t)B_ * HP * WPAD * (64 + 128 + 64) * 2, stream);

  wxform<<<900, 256, 0, stream>>>(w_off, w_dcn, w_r1, w_r2, wOffB, wDcnB, wR1B, wR2B);
  to_nhwc<64,  true ><<<dim3(12, 384), 256, 0, stream>>>(offin, offs_t, 0);
  to_nhwc<128, true ><<<dim3(12, 384), 256, 0, stream>>>(prev,  concat_t, 64);

  // K1: offset conv (64 -> 144), bf16 NCHW out.
  conv_mfma<64, 144, 9, false, 0, true><<<dim3(3, 384), 256, 0, stream>>>(
      offs_t, wOffB, b_off, nullptr, offf);

  // prev -> group-planar (overwrites offs_t region; K1 is done with it)
  to_gp<<<2304, 256, 0, stream>>>(prev, gp);

  // K2: deformable conv -> concat_t channels [0,64). Barrier-free.
  deform_mfma<<<1152, 256, 0, stream>>>(gp, offf, wDcnB, b_dcn, concat_t);

  // K3: r1 = leaky(conv(concat)) (128 -> 64), NHWC padded out.
  conv_mfma<128, 64, 4, true, 1, false><<<dim3(3, 384), 256, 0, stream>>>(
      concat_t, wR1B, b_r1, nullptr, r1_t);

  // K4: out = aligned + leaky(conv(r1)) (64 -> 64), f32 NCHW out.
  conv_mfma<64, 64, 4, true, 2, true><<<dim3(3, 384), 256, 0, stream>>>(
      r1_t, wR2B, b_r2, concat_t, out);
}

// Round 8
// 176.130 us; speedup vs baseline: 1.0464x; 1.0464x over previous
//
#include <hip/hip_runtime.h>
#include <hip/hip_bf16.h>
#include <cstdint>
#include <cstddef>

constexpr int B_ = 2;
constexpr int HH = 192, WW = 192, HW_ = HH * WW;
constexpr int HP = 194, WPAD = 200;   // padded dims

typedef short bf16x8 __attribute__((ext_vector_type(8)));
typedef short s16x4  __attribute__((ext_vector_type(4)));
typedef float f32x4  __attribute__((ext_vector_type(4)));

typedef __attribute__((address_space(1))) const void GLB;
typedef __attribute__((address_space(3))) void LDS;

__device__ __forceinline__ float bf2f(unsigned short h) {
  union { unsigned u; float f; } v; v.u = (unsigned)h << 16; return v.f;
}
__device__ __forceinline__ unsigned short f2bf(float f) {
  union { float f; unsigned u; } v; v.f = f;
  unsigned u = v.u;
  u += 0x7fffu + ((u >> 16) & 1u);
  return (unsigned short)(u >> 16);
}
__device__ __forceinline__ float leaky(float v) { return fmaxf(v, 0.1f * v); }

// ---------------------------------------------------------------------------
// NCHW f32 -> NHWC bf16 (padded interior of [HP][WPAD]).
// ---------------------------------------------------------------------------
template<int DSTC, bool PAD>
__global__ __launch_bounds__(256) void to_nhwc(const float* __restrict__ src,
                                               unsigned short* __restrict__ dst,
                                               int coff)
{
  __shared__ float tile[16][65];
  int t = threadIdx.x;
  int xc = blockIdx.x * 16;
  int y = blockIdx.y % HH, b = blockIdx.y / HH;
  #pragma unroll
  for (int cp = 0; cp < 4; ++cp) {
    int c = cp * 16 + (t >> 4);
    tile[t & 15][c] = src[((size_t)(b * 64 + c) * HH + y) * WW + xc + (t & 15)];
  }
  __syncthreads();
  int x = t >> 4, c4 = (t & 15) * 4;
  s16x4 s;
  #pragma unroll
  for (int j = 0; j < 4; ++j) s[j] = (short)f2bf(tile[x][c4 + j]);
  size_t pbase = PAD
      ? ((size_t)(b * HP + y + 1) * WPAD + xc + x + 1) * DSTC + coff + c4
      : ((size_t)(b * HH + y) * WW + xc + x) * DSTC + coff + c4;
  *(s16x4*)&dst[pbase] = s;
}

// ---------------------------------------------------------------------------
// prev NCHW f32 -> group-planar bf16 [b][8][192][192][8]  (for deform window)
// ---------------------------------------------------------------------------
__global__ __launch_bounds__(256) void to_gp(const float* __restrict__ src,
                                             unsigned short* __restrict__ gp)
{
  int tid = blockIdx.x * 256 + threadIdx.x;     // 589824 = 2304 * 256 exact
  int x = tid % WW;
  int y = (tid / WW) % HH;
  int g = (tid / HW_) % 8;
  int b = tid / (8 * HW_);
  const float* sp = src + ((size_t)(b * 64 + g * 8) * HH + y) * WW + x;
  bf16x8 v;
  #pragma unroll
  for (int c = 0; c < 8; ++c) v[c] = (short)f2bf(sp[(size_t)c * HW_]);
  *(bf16x8*)&gp[(size_t)tid * 8] = v;
}

// ---------------------------------------------------------------------------
// Weight transform: (O, CI, 3, 3) f32 -> tap-major [k][o][ci] bf16.
// K1/K3/K4 images get the LDS XOR bank-swizzle; deform (w_dcn) stays plain.
// ---------------------------------------------------------------------------
__global__ __launch_bounds__(256) void wxform(
    const float* __restrict__ w_off, const float* __restrict__ w_dcn,
    const float* __restrict__ w_r1,  const float* __restrict__ w_r2,
    unsigned short* __restrict__ wOffB, unsigned short* __restrict__ wDcnB,
    unsigned short* __restrict__ wR1B,  unsigned short* __restrict__ wR2B)
{
  int tid = blockIdx.x * 256 + threadIdx.x;   // 230400 total
  const float* src; unsigned short* dst; int CI, CO, idx; bool dosw = true;
  if (tid < 82944)            { src = w_off; dst = wOffB; CI = 64;  CO = 144; idx = tid; }
  else if (tid < 119808)      { src = w_dcn; dst = wDcnB; CI = 64;  CO = 64;  idx = tid - 82944; dosw = false; }
  else if (tid < 193536)      { src = w_r1;  dst = wR1B;  CI = 128; CO = 64;  idx = tid - 119808; }
  else                        { src = w_r2;  dst = wR2B;  CI = 64;  CO = 64;  idx = tid - 193536; }
  int ci = idx % CI;
  int k  = (idx / CI) % 9;
  int o  = idx / (CI * 9);
  int pci = dosw ? (((((ci >> 3) ^ (o & 7))) << 3) | (ci & 7)) : ci;
  dst[((size_t)k * CO + o) * CI + pci] = f2bf(src[((size_t)o * CI + ci) * 9 + k]);
}

// ---------------------------------------------------------------------------
// MFMA implicit-GEMM 3x3 conv. Pixels staged once in LDS; per-tap weights
// staged in LDS via global_load_lds (DBUF: double-buffered, 1 barrier/tap).
// OUTMODE 0: bf16 NCHW (K1) | 1: bf16 NHWC padded (K3) | 2: f32 NCHW + resid (K4)
// ---------------------------------------------------------------------------
template<int CIN, int COUT, int NF, bool LEAKY_, int OUTMODE, bool DBUF>
__global__ __launch_bounds__(256, 4) void conv_mfma(
    const unsigned short* __restrict__ inT,   // [b][HP][WPAD][CIN] bf16
    const unsigned short* __restrict__ wS,    // [9][COUT][CIN] bf16, swizzled image
    const float* __restrict__ bias,
    const unsigned short* __restrict__ resid,
    void* __restrict__ outp)
{
  constexpr int CPP  = CIN / 8;          // 16B chunks per pixel
  constexpr int TPX  = 72;
  constexpr int NCH  = TPX * CPP;        // chunks per staged row
  constexpr int RPR  = NCH / 64;         // wave-regions per row
  constexpr int NREG = 3 * RPR;
  constexpr int WSZ  = COUT * CIN;       // weight elems per tap
  constexpr int WCH  = WSZ / 8;          // 16B chunks per tap
  __shared__ __align__(16) unsigned short tile[3 * TPX * CIN];
  __shared__ __align__(16) unsigned short wlds[(DBUF ? 2 : 1) * WSZ];

  const int t = threadIdx.x;
  const int l = t & 63, wv = t >> 6;
  const int lr = l & 15, lq = l >> 4, lk = lq * 8;

  // XCD-aware bijective swizzle (1152 % 8 == 0)
  constexpr int NWG = 3 * 384;
  int lin = blockIdx.x + 3 * blockIdx.y;
  int swz = (lin & 7) * (NWG / 8) + (lin >> 3);
  int xq = swz % 3, yy = swz / 3;
  int y = yy % HH, b = yy / HH;
  int x0 = xq * 64;

  // ---- stage 3 pixel rows (72 px each, swizzled) + weight tap 0
  {
    const unsigned short* base = inT + ((size_t)(b * HP + y) * WPAD + x0) * CIN;
    for (int r = wv; r < NREG; r += 4) {
      int row = r / RPR;
      int rr  = r % RPR;
      int d   = rr * 64 + l;
      int p   = d / CPP;
      int cj  = d % CPP;
      int sc  = p * CPP + (cj ^ (p & (CPP - 1)));
      const unsigned short* src = base + (size_t)row * WPAD * CIN + (size_t)sc * 8;
      unsigned short* dst = &tile[(size_t)(row * NCH + rr * 64) * 8];
      __builtin_amdgcn_global_load_lds((GLB*)src, (LDS*)dst, 16, 0, 0);
    }
  }
  {
    const unsigned short* srcb = wS;                 // tap 0
    for (int r = t; r < WCH; r += 256)
      __builtin_amdgcn_global_load_lds((GLB*)(srcb + (size_t)r * 8),
                                       (LDS*)(&wlds[(size_t)r * 8]), 16, 0, 0);
  }
  __syncthreads();

  f32x4 acc[NF];
  #pragma unroll
  for (int f = 0; f < NF; ++f) acc[f] = f32x4{0.f, 0.f, 0.f, 0.f};

  #pragma unroll
  for (int k = 0; k < 9; ++k) {
    const int ky = k / 3, kx = k % 3;
    if (DBUF && k < 8) {
      const unsigned short* srcb = wS + (size_t)(k + 1) * WSZ;
      unsigned short* db = &wlds[(size_t)((k + 1) & 1) * WSZ];
      for (int r = t; r < WCH; r += 256)
        __builtin_amdgcn_global_load_lds((GLB*)(srcb + (size_t)r * 8),
                                         (LDS*)(db + (size_t)r * 8), 16, 0, 0);
    }
    // ---- compute tap k
    {
      const unsigned short* wb = &wlds[DBUF ? (size_t)(k & 1) * WSZ : 0];
      const int px = wv * 16 + lr + kx;
      #pragma unroll
      for (int c = 0; c < CIN; c += 32) {
        int cj = (c + lk) >> 3;
        bf16x8 pf = *(const bf16x8*)
            &tile[(size_t)(ky * NCH + px * CPP + (cj ^ (px & (CPP - 1)))) * 8];
        #pragma unroll
        for (int f = 0; f < NF; ++f) {
          int co = f * 16 + lr;
          bf16x8 wf = *(const bf16x8*)&wb[(size_t)co * CIN + ((cj ^ (co & 7)) << 3)];
          if (OUTMODE == 0)
            acc[f] = __builtin_amdgcn_mfma_f32_16x16x32_bf16(pf, wf, acc[f], 0, 0, 0);
          else
            acc[f] = __builtin_amdgcn_mfma_f32_16x16x32_bf16(wf, pf, acc[f], 0, 0, 0);
        }
      }
    }
    if (DBUF) {
      __syncthreads();
    } else if (k < 8) {
      __syncthreads();                       // all reads of wlds done
      const unsigned short* srcb = wS + (size_t)(k + 1) * WSZ;
      for (int r = t; r < WCH; r += 256)
        __builtin_amdgcn_global_load_lds((GLB*)(srcb + (size_t)r * 8),
                                         (LDS*)(&wlds[(size_t)r * 8]), 16, 0, 0);
      __syncthreads();                       // staging complete
    }
  }

  if (OUTMODE == 0) {
    int xs = x0 + wv * 16 + lq * 4;
    #pragma unroll
    for (int f = 0; f < NF; ++f) {
      int co = f * 16 + lr;
      float bv = bias[co];
      s16x4 s;
      #pragma unroll
      for (int j = 0; j < 4; ++j) {
        float v = acc[f][j] + bv;
        if (LEAKY_) v = leaky(v);
        s[j] = (short)f2bf(v);
      }
      *(s16x4*)((unsigned short*)outp + ((size_t)(b * COUT + co) * HH + y) * WW + xs) = s;
    }
  } else if (OUTMODE == 1) {
    int x = x0 + wv * 16 + lr;
    #pragma unroll
    for (int f = 0; f < NF; ++f) {
      int co = f * 16 + lq * 4;
      f32x4 bv = *(const f32x4*)&bias[co];
      s16x4 s;
      #pragma unroll
      for (int j = 0; j < 4; ++j) {
        float v = acc[f][j] + bv[j];
        if (LEAKY_) v = leaky(v);
        s[j] = (short)f2bf(v);
      }
      *(s16x4*)((unsigned short*)outp + ((size_t)(b * HP + y + 1) * WPAD + x + 1) * 64 + co) = s;
    }
  } else {
    int x = x0 + wv * 16 + lr;
    const unsigned short* rbase = resid + ((size_t)(b * HP + y + 1) * WPAD + x + 1) * 128;
    float* ob = (float*)outp + (size_t)b * 64 * HW_ + (size_t)y * WW + x;
    #pragma unroll
    for (int f = 0; f < NF; ++f) {
      int cob = f * 16 + lq * 4;
      f32x4 bv = *(const f32x4*)&bias[cob];
      s16x4 rv = *(const s16x4*)&rbase[cob];
      #pragma unroll
      for (int j = 0; j < 4; ++j) {
        float v = acc[f][j] + bv[j];
        if (LEAKY_) v = leaky(v);
        v += bf2f((unsigned short)rv[j]);
        ob[(size_t)(cob + j) * HW_] = v;
      }
    }
  }
}

// ---------------------------------------------------------------------------
// Deformable conv, LDS-window design. Stage a 6-row x 72-col x 8-group window
// of gp into LDS (clamp-replicated borders; duplicate slots provably never
// addressed because sample coords clamp to [0,191] first). All bilinear reads
// become ds_read_b128. Per-lane out-of-window predicate -> rare wave-uniform
// global-gather fallback keeps exact semantics for any offset magnitude.
// ---------------------------------------------------------------------------
__global__ __launch_bounds__(256, 2) void deform_mfma(
    const unsigned short* __restrict__ gp,    // [b][8][192][192][8] bf16
    const unsigned short* __restrict__ off,   // [b][144][192][192] bf16
    const unsigned short* __restrict__ wD,    // [9][64][64] bf16 plain
    const float* __restrict__ bias,
    unsigned short* __restrict__ concatT)     // [b][HP][WPAD][128], writes ch0-63
{
  __shared__ __align__(16) unsigned short win[8 * 6 * 72 * 8];   // 55.3 KB [g][r][c][ch]
  const int t = threadIdx.x;
  const int l = t & 63, wv = t >> 6;
  const int lr = l & 15, lq = l >> 4;

  int lin = blockIdx.x;                       // 1152 blocks
  int swz = (lin & 7) * 144 + (lin >> 3);     // XCD-aware bijective
  int xq = swz % 3, yy = swz / 3;
  int y = yy % HH, b = yy / HH;
  int x0 = xq * 64;
  int xpix = x0 + wv * 16 + lr;               // this lane's pixel

  const int wy = y - 2, wx = x0 - 3;          // window origin (image coords)
  const unsigned short* gpb = gp + (size_t)b * 8 * HW_ * 8;

  // ---- stage window: 3456 slots x 16B, coalesced, clamp-replicated
  for (int s = t; s < 3456; s += 256) {
    int g  = s / 432;                         // 432 = 6*72 slots per group
    int rc = s - g * 432;
    int r  = rc / 72;
    int c  = rc - r * 72;
    int yr = min(max(wy + r, 0), HH - 1);
    int xc = min(max(wx + c, 0), WW - 1);
    const unsigned short* src = gpb + ((size_t)g * HW_ + (size_t)yr * WW + xc) * 8;
    __builtin_amdgcn_global_load_lds((GLB*)src, (LDS*)(win + (size_t)s * 8), 16, 0, 0);
  }

  // ---- preload offsets, packed (dy | dx<<16) per (group-pair, tap)
  unsigned dd[2][9];
  #pragma unroll
  for (int gi = 0; gi < 2; ++gi) {
    int g = lq + gi * 4;
    const unsigned short* op = off + ((size_t)(b * 144 + g * 18) * HH + y) * WW + xpix;
    #pragma unroll
    for (int k = 0; k < 9; ++k) {
      unsigned dyv = op[(size_t)(2 * k) * HW_];
      unsigned dxv = op[(size_t)(2 * k + 1) * HW_];
      dd[gi][k] = dyv | (dxv << 16);
    }
  }

  __syncthreads();                            // window ready (single barrier)

  f32x4 acc[4];
  #pragma unroll
  for (int f = 0; f < 4; ++f) acc[f] = f32x4{0.f, 0.f, 0.f, 0.f};

  #pragma unroll
  for (int k = 0; k < 9; ++k) {
    const int ky = k / 3, kx = k % 3;
    bf16x8 pf0, pf1;
    #pragma unroll
    for (int gi = 0; gi < 2; ++gi) {
      int g = lq + gi * 4;
      float dyv = bf2f((unsigned short)(dd[gi][k] & 0xffffu));
      float dxv = bf2f((unsigned short)(dd[gi][k] >> 16));
      float py = (float)(y - 1 + ky) + dyv;
      float px = (float)(xpix - 1 + kx) + dxv;
      float fy0 = floorf(py), fx0 = floorf(px);
      float wy1 = py - fy0, wx1 = px - fx0;
      float wy0 = 1.f - wy1, wx0 = 1.f - wx1;
      bool vy0 = (fy0 >= 0.f)  && (fy0 <= 191.f);
      bool vy1 = (fy0 >= -1.f) && (fy0 <= 190.f);
      bool vx0 = (fx0 >= 0.f)  && (fx0 <= 191.f);
      bool vx1 = (fx0 >= -1.f) && (fx0 <= 190.f);
      float c00 = (vy0 && vx0) ? wy0 * wx0 : 0.f;
      float c01 = (vy0 && vx1) ? wy0 * wx1 : 0.f;
      float c10 = (vy1 && vx0) ? wy1 * wx0 : 0.f;
      float c11 = (vy1 && vx1) ? wy1 * wx1 : 0.f;
      int iy0 = (int)fminf(fmaxf(fy0, 0.f), 191.f);
      int iy1 = (int)fminf(fmaxf(fy0 + 1.f, 0.f), 191.f);
      int ix0 = (int)fminf(fmaxf(fx0, 0.f), 191.f);
      int ix1 = (int)fminf(fmaxf(fx0 + 1.f, 0.f), 191.f);
      bool inw = (iy0 >= wy) && (iy1 <= wy + 5) && (ix0 >= wx) && (ix1 <= wx + 71);
      int ry0 = min(max(iy0 - wy, 0), 5), ry1 = min(max(iy1 - wy, 0), 5);
      int rx0 = min(max(ix0 - wx, 0), 71), rx1 = min(max(ix1 - wx, 0), 71);
      const unsigned short* wg = win + (size_t)g * 3456;       // 432 slots * 8
      bf16x8 v00 = *(const bf16x8*)(wg + ((size_t)ry0 * 72 + rx0) * 8);
      bf16x8 v01 = *(const bf16x8*)(wg + ((size_t)ry0 * 72 + rx1) * 8);
      bf16x8 v10 = *(const bf16x8*)(wg + ((size_t)ry1 * 72 + rx0) * 8);
      bf16x8 v11 = *(const bf16x8*)(wg + ((size_t)ry1 * 72 + rx1) * 8);
      if (!__all((int)inw)) {                 // rare: exact global fallback
        if (!inw) {
          const unsigned short* bb = gpb + (size_t)g * HW_ * 8;
          v00 = *(const bf16x8*)(bb + ((size_t)iy0 * WW + ix0) * 8);
          v01 = *(const bf16x8*)(bb + ((size_t)iy0 * WW + ix1) * 8);
          v10 = *(const bf16x8*)(bb + ((size_t)iy1 * WW + ix0) * 8);
          v11 = *(const bf16x8*)(bb + ((size_t)iy1 * WW + ix1) * 8);
        }
      }
      bf16x8 sv;
      #pragma unroll
      for (int j = 0; j < 8; ++j) {
        float s = bf2f((unsigned short)v00[j]) * c00
                + bf2f((unsigned short)v01[j]) * c01
                + bf2f((unsigned short)v10[j]) * c10
                + bf2f((unsigned short)v11[j]) * c11;
        sv[j] = (short)f2bf(s);
      }
      if (gi == 0) pf0 = sv; else pf1 = sv;
    }
    #pragma unroll
    for (int f = 0; f < 4; ++f) {
      bf16x8 wf = *(const bf16x8*)&wD[((size_t)k * 64 + f * 16 + lr) * 64 + lq * 8];
      acc[f] = __builtin_amdgcn_mfma_f32_16x16x32_bf16(wf, pf0, acc[f], 0, 0, 0);
    }
    #pragma unroll
    for (int f = 0; f < 4; ++f) {
      bf16x8 wf = *(const bf16x8*)&wD[((size_t)k * 64 + f * 16 + lr) * 64 + 32 + lq * 8];
      acc[f] = __builtin_amdgcn_mfma_f32_16x16x32_bf16(wf, pf1, acc[f], 0, 0, 0);
    }
  }

  // epilogue: NHWC bf16 into concat channels [0,64). C: col=pixel=lr, row=lq*4+j
  unsigned short* outc = concatT + (size_t)b * HP * WPAD * 128;
  #pragma unroll
  for (int f = 0; f < 4; ++f) {
    int co = f * 16 + lq * 4;
    f32x4 bv = *(const f32x4*)&bias[co];
    s16x4 s;
    #pragma unroll
    for (int j = 0; j < 4; ++j) s[j] = (short)f2bf(acc[f][j] + bv[j]);
    *(s16x4*)&outc[((size_t)(y + 1) * WPAD + xpix + 1) * 128 + co] = s;
  }
}

// ---------------------------------------------------------------------------
extern "C" void kernel_launch(void* const* d_in, const int* in_sizes, int n_in,
                              void* d_out, int out_size, void* d_ws, size_t ws_size,
                              hipStream_t stream)
{
  const float* prev  = (const float*)d_in[0];
  const float* offin = (const float*)d_in[1];
  const float* w_off = (const float*)d_in[2];
  const float* b_off = (const float*)d_in[3];
  const float* w_dcn = (const float*)d_in[4];
  const float* b_dcn = (const float*)d_in[5];
  const float* w_r1  = (const float*)d_in[6];
  const float* b_r1  = (const float*)d_in[7];
  const float* w_r2  = (const float*)d_in[8];
  const float* b_r2  = (const float*)d_in[9];
  float* out = (float*)d_out;

  char* p = (char*)d_ws;
  unsigned short* offs_t   = (unsigned short*)p; p += (size_t)B_ * HP * WPAD * 64 * 2;   //  9.93 MB
  unsigned short* concat_t = (unsigned short*)p; p += (size_t)B_ * HP * WPAD * 128 * 2;  // 19.87 MB
  unsigned short* r1_t     = (unsigned short*)p; p += (size_t)B_ * HP * WPAD * 64 * 2;   //  9.93 MB
  unsigned short* offf     = (unsigned short*)p; p += (size_t)B_ * 144 * HW_ * 2;        // 21.23 MB
  unsigned short* wOffB    = (unsigned short*)p; p += 144 * 576 * 2;
  unsigned short* wDcnB    = (unsigned short*)p; p += 64 * 576 * 2;
  unsigned short* wR1B     = (unsigned short*)p; p += 64 * 1152 * 2;
  unsigned short* wR2B     = (unsigned short*)p; p += 64 * 576 * 2;                      // total ~61.4 MB
  // gp (group-planar prev, 9.44 MB) aliases offs_t (9.93 MB): offs_t is dead
  // after K1, and to_gp runs after K1 on the same stream.
  unsigned short* gp = offs_t;

  // Zero padded NHWC buffers (contiguous) so pad borders are 0.
  hipMemsetAsync(offs_t, 0, (size_t)B_ * HP * WPAD * (64 + 128 + 64) * 2, stream);

  wxform<<<900, 256, 0, stream>>>(w_off, w_dcn, w_r1, w_r2, wOffB, wDcnB, wR1B, wR2B);
  to_nhwc<64,  true ><<<dim3(12, 384), 256, 0, stream>>>(offin, offs_t, 0);
  to_nhwc<128, true ><<<dim3(12, 384), 256, 0, stream>>>(prev,  concat_t, 64);

  // K1: offset conv (64 -> 144), bf16 NCHW out.
  conv_mfma<64, 144, 9, false, 0, true><<<dim3(3, 384), 256, 0, stream>>>(
      offs_t, wOffB, b_off, nullptr, offf);

  // prev -> group-planar (overwrites offs_t region; K1 is done with it)
  to_gp<<<2304, 256, 0, stream>>>(prev, gp);

  // K2: deformable conv -> concat_t channels [0,64). LDS-window sampling.
  deform_mfma<<<1152, 256, 0, stream>>>(gp, offf, wDcnB, b_dcn, concat_t);

  // K3: r1 = leaky(conv(concat)) (128 -> 64), NHWC padded out.
  conv_mfma<128, 64, 4, true, 1, false><<<dim3(3, 384), 256, 0, stream>>>(
      concat_t, wR1B, b_r1, nullptr, r1_t);

  // K4: out = aligned + leaky(conv(r1)) (64 -> 64), f32 NCHW out.
  conv_mfma<64, 64, 4, true, 2, true><<<dim3(3, 384), 256, 0, stream>>>(
      r1_t, wR2B, b_r2, concat_t, out);
}

// Round 11
// 174.227 us; speedup vs baseline: 1.0578x; 1.0109x over previous
//
#include <hip/hip_runtime.h>
#include <hip/hip_bf16.h>
#include <cstdint>
#include <cstddef>

constexpr int B_ = 2;
constexpr int HH = 192, WW = 192, HW_ = HH * WW;
constexpr int HP = 194, WPAD = 200;   // padded dims

typedef short bf16x8 __attribute__((ext_vector_type(8)));
typedef short s16x4  __attribute__((ext_vector_type(4)));
typedef float f32x4  __attribute__((ext_vector_type(4)));

typedef __attribute__((address_space(1))) const void GLB;
typedef __attribute__((address_space(3))) void LDS;

__device__ __forceinline__ float bf2f(unsigned short h) {
  union { unsigned u; float f; } v; v.u = (unsigned)h << 16; return v.f;
}
__device__ __forceinline__ unsigned short f2bf(float f) {
  union { float f; unsigned u; } v; v.f = f;
  unsigned u = v.u;
  u += 0x7fffu + ((u >> 16) & 1u);
  return (unsigned short)(u >> 16);
}
__device__ __forceinline__ float leaky(float v) { return fmaxf(v, 0.1f * v); }

// ---------------------------------------------------------------------------
// NCHW f32 -> NHWC bf16 (padded interior of [HP][WPAD]).
// ---------------------------------------------------------------------------
template<int DSTC, bool PAD>
__global__ __launch_bounds__(256) void to_nhwc(const float* __restrict__ src,
                                               unsigned short* __restrict__ dst,
                                               int coff)
{
  __shared__ float tile[16][65];
  int t = threadIdx.x;
  int xc = blockIdx.x * 16;
  int y = blockIdx.y % HH, b = blockIdx.y / HH;
  #pragma unroll
  for (int cp = 0; cp < 4; ++cp) {
    int c = cp * 16 + (t >> 4);
    tile[t & 15][c] = src[((size_t)(b * 64 + c) * HH + y) * WW + xc + (t & 15)];
  }
  __syncthreads();
  int x = t >> 4, c4 = (t & 15) * 4;
  s16x4 s;
  #pragma unroll
  for (int j = 0; j < 4; ++j) s[j] = (short)f2bf(tile[x][c4 + j]);
  size_t pbase = PAD
      ? ((size_t)(b * HP + y + 1) * WPAD + xc + x + 1) * DSTC + coff + c4
      : ((size_t)(b * HH + y) * WW + xc + x) * DSTC + coff + c4;
  *(s16x4*)&dst[pbase] = s;
}

// ---------------------------------------------------------------------------
// prev NCHW f32 -> group-planar bf16 [b][8][192][192][8]  (for deform window)
// ---------------------------------------------------------------------------
__global__ __launch_bounds__(256) void to_gp(const float* __restrict__ src,
                                             unsigned short* __restrict__ gp)
{
  int tid = blockIdx.x * 256 + threadIdx.x;     // 589824 = 2304 * 256 exact
  int x = tid % WW;
  int y = (tid / WW) % HH;
  int g = (tid / HW_) % 8;
  int b = tid / (8 * HW_);
  const float* sp = src + ((size_t)(b * 64 + g * 8) * HH + y) * WW + x;
  bf16x8 v;
  #pragma unroll
  for (int c = 0; c < 8; ++c) v[c] = (short)f2bf(sp[(size_t)c * HW_]);
  *(bf16x8*)&gp[(size_t)tid * 8] = v;
}

// ---------------------------------------------------------------------------
// Weight transform: (O, CI, 3, 3) f32 -> tap-major [k][o][ci] bf16.
// K1/K3/K4 images get the LDS XOR bank-swizzle; deform (w_dcn) stays plain.
// ---------------------------------------------------------------------------
__global__ __launch_bounds__(256) void wxform(
    const float* __restrict__ w_off, const float* __restrict__ w_dcn,
    const float* __restrict__ w_r1,  const float* __restrict__ w_r2,
    unsigned short* __restrict__ wOffB, unsigned short* __restrict__ wDcnB,
    unsigned short* __restrict__ wR1B,  unsigned short* __restrict__ wR2B)
{
  int tid = blockIdx.x * 256 + threadIdx.x;   // 230400 total
  const float* src; unsigned short* dst; int CI, CO, idx; bool dosw = true;
  if (tid < 82944)            { src = w_off; dst = wOffB; CI = 64;  CO = 144; idx = tid; }
  else if (tid < 119808)      { src = w_dcn; dst = wDcnB; CI = 64;  CO = 64;  idx = tid - 82944; dosw = false; }
  else if (tid < 193536)      { src = w_r1;  dst = wR1B;  CI = 128; CO = 64;  idx = tid - 119808; }
  else                        { src = w_r2;  dst = wR2B;  CI = 64;  CO = 64;  idx = tid - 193536; }
  int ci = idx % CI;
  int k  = (idx / CI) % 9;
  int o  = idx / (CI * 9);
  int pci = dosw ? (((((ci >> 3) ^ (o & 7))) << 3) | (ci & 7)) : ci;
  dst[((size_t)k * CO + o) * CI + pci] = f2bf(src[((size_t)o * CI + ci) * 9 + k]);
}

// ---------------------------------------------------------------------------
// MFMA implicit-GEMM 3x3 conv. Pixels staged once in LDS; per-tap weights
// staged in LDS via global_load_lds (DBUF: double-buffered, 1 barrier/tap).
// OUTMODE 0: bf16 NCHW (K1) | 1: bf16 NHWC padded (K3) | 2: f32 NCHW + resid (K4)
// ---------------------------------------------------------------------------
template<int CIN, int COUT, int NF, bool LEAKY_, int OUTMODE, bool DBUF>
__global__ __launch_bounds__(256, 4) void conv_mfma(
    const unsigned short* __restrict__ inT,   // [b][HP][WPAD][CIN] bf16
    const unsigned short* __restrict__ wS,    // [9][COUT][CIN] bf16, swizzled image
    const float* __restrict__ bias,
    const unsigned short* __restrict__ resid,
    void* __restrict__ outp)
{
  constexpr int CPP  = CIN / 8;          // 16B chunks per pixel
  constexpr int TPX  = 72;
  constexpr int NCH  = TPX * CPP;        // chunks per staged row
  constexpr int RPR  = NCH / 64;         // wave-regions per row
  constexpr int NREG = 3 * RPR;
  constexpr int WSZ  = COUT * CIN;       // weight elems per tap
  constexpr int WCH  = WSZ / 8;          // 16B chunks per tap (always mult of 128)
  __shared__ __align__(16) unsigned short tile[3 * TPX * CIN];
  __shared__ __align__(16) unsigned short wlds[(DBUF ? 2 : 1) * WSZ];

  const int t = threadIdx.x;
  const int l = t & 63, wv = t >> 6;
  const int lr = l & 15, lq = l >> 4, lk = lq * 8;

  // XCD-aware bijective swizzle (1152 % 8 == 0)
  constexpr int NWG = 3 * 384;
  int lin = blockIdx.x + 3 * blockIdx.y;
  int swz = (lin & 7) * (NWG / 8) + (lin >> 3);
  int xq = swz % 3, yy = swz / 3;
  int y = yy % HH, b = yy / HH;
  int x0 = xq * 64;

  // ---- stage 3 pixel rows (72 px each, swizzled) + weight tap 0
  {
    const unsigned short* base = inT + ((size_t)(b * HP + y) * WPAD + x0) * CIN;
    for (int r = wv; r < NREG; r += 4) {
      int row = r / RPR;
      int rr  = r % RPR;
      int d   = rr * 64 + l;
      int p   = d / CPP;
      int cj  = d % CPP;
      int sc  = p * CPP + (cj ^ (p & (CPP - 1)));
      const unsigned short* src = base + (size_t)row * WPAD * CIN + (size_t)sc * 8;
      unsigned short* dst = &tile[(size_t)(row * NCH + rr * 64) * 8];
      __builtin_amdgcn_global_load_lds((GLB*)src, (LDS*)dst, 16, 0, 0);
    }
  }
  {
    const unsigned short* srcb = wS;                 // tap 0
    for (int r = t; r < WCH; r += 256)
      __builtin_amdgcn_global_load_lds((GLB*)(srcb + (size_t)r * 8),
                                       (LDS*)(&wlds[(size_t)r * 8]), 16, 0, 0);
  }
  __syncthreads();

  f32x4 acc[NF];
  #pragma unroll
  for (int f = 0; f < NF; ++f) acc[f] = f32x4{0.f, 0.f, 0.f, 0.f};

  #pragma unroll
  for (int k = 0; k < 9; ++k) {
    const int ky = k / 3, kx = k % 3;
    if (DBUF && k < 8) {
      const unsigned short* srcb = wS + (size_t)(k + 1) * WSZ;
      unsigned short* db = &wlds[(size_t)((k + 1) & 1) * WSZ];
      for (int r = t; r < WCH; r += 256)
        __builtin_amdgcn_global_load_lds((GLB*)(srcb + (size_t)r * 8),
                                         (LDS*)(db + (size_t)r * 8), 16, 0, 0);
    }
    // ---- compute tap k
    {
      const unsigned short* wb = &wlds[DBUF ? (size_t)(k & 1) * WSZ : 0];
      const int px = wv * 16 + lr + kx;
      #pragma unroll
      for (int c = 0; c < CIN; c += 32) {
        int cj = (c + lk) >> 3;
        bf16x8 pf = *(const bf16x8*)
            &tile[(size_t)(ky * NCH + px * CPP + (cj ^ (px & (CPP - 1)))) * 8];
        #pragma unroll
        for (int f = 0; f < NF; ++f) {
          int co = f * 16 + lr;
          bf16x8 wf = *(const bf16x8*)&wb[(size_t)co * CIN + ((cj ^ (co & 7)) << 3)];
          if (OUTMODE == 0)
            acc[f] = __builtin_amdgcn_mfma_f32_16x16x32_bf16(pf, wf, acc[f], 0, 0, 0);
          else
            acc[f] = __builtin_amdgcn_mfma_f32_16x16x32_bf16(wf, pf, acc[f], 0, 0, 0);
        }
      }
    }
    if (DBUF) {
      __syncthreads();
    } else if (k < 8) {
      __syncthreads();                       // all reads of wlds done
      const unsigned short* srcb = wS + (size_t)(k + 1) * WSZ;
      for (int r = t; r < WCH; r += 256)
        __builtin_amdgcn_global_load_lds((GLB*)(srcb + (size_t)r * 8),
                                         (LDS*)(&wlds[(size_t)r * 8]), 16, 0, 0);
      __syncthreads();                       // staging complete
    }
  }

  if (OUTMODE == 0) {
    int xs = x0 + wv * 16 + lq * 4;
    #pragma unroll
    for (int f = 0; f < NF; ++f) {
      int co = f * 16 + lr;
      float bv = bias[co];
      s16x4 s;
      #pragma unroll
      for (int j = 0; j < 4; ++j) {
        float v = acc[f][j] + bv;
        if (LEAKY_) v = leaky(v);
        s[j] = (short)f2bf(v);
      }
      *(s16x4*)((unsigned short*)outp + ((size_t)(b * COUT + co) * HH + y) * WW + xs) = s;
    }
  } else if (OUTMODE == 1) {
    int x = x0 + wv * 16 + lr;
    #pragma unroll
    for (int f = 0; f < NF; ++f) {
      int co = f * 16 + lq * 4;
      f32x4 bv = *(const f32x4*)&bias[co];
      s16x4 s;
      #pragma unroll
      for (int j = 0; j < 4; ++j) {
        float v = acc[f][j] + bv[j];
        if (LEAKY_) v = leaky(v);
        s[j] = (short)f2bf(v);
      }
      *(s16x4*)((unsigned short*)outp + ((size_t)(b * HP + y + 1) * WPAD + x + 1) * 64 + co) = s;
    }
  } else {
    int x = x0 + wv * 16 + lr;
    const unsigned short* rbase = resid + ((size_t)(b * HP + y + 1) * WPAD + x + 1) * 128;
    float* ob = (float*)outp + (size_t)b * 64 * HW_ + (size_t)y * WW + x;
    #pragma unroll
    for (int f = 0; f < NF; ++f) {
      int cob = f * 16 + lq * 4;
      f32x4 bv = *(const f32x4*)&bias[cob];
      s16x4 rv = *(const s16x4*)&rbase[cob];
      #pragma unroll
      for (int j = 0; j < 4; ++j) {
        float v = acc[f][j] + bv[j];
        if (LEAKY_) v = leaky(v);
        v += bf2f((unsigned short)rv[j]);
        ob[(size_t)(cob + j) * HW_] = v;
      }
    }
  }
}

// ---------------------------------------------------------------------------
// Deformable conv, LDS-window, 2-row x 32-col tile.
// Window: 6 rows x 40 cols x 8 groups, group stride 241 slots (bank tilt).
// STAGING (R10 post-timing fix): slot space padded to 2048 = 8*256 so EVERY
// global_load_lds iteration runs with a fully-active wave (partial-wave
// masking with this instruction risks LDS writes past the allocation).
// Pad slots (p >= 1928 and rc == 240) load clamped valid sources, never read.
// ---------------------------------------------------------------------------
__global__ __launch_bounds__(256, 4) void deform_mfma(
    const unsigned short* __restrict__ gp,    // [b][8][192][192][8] bf16
    const unsigned short* __restrict__ off,   // [b][144][192][192] bf16
    const unsigned short* __restrict__ wD,    // [9][64][64] bf16 plain
    const float* __restrict__ bias,
    unsigned short* __restrict__ concatT)     // [b][HP][WPAD][128], writes ch0-63
{
  __shared__ __align__(16) unsigned short win[2048 * 8];   // 32768 B
  const int t = threadIdx.x;
  const int l = t & 63, wv = t >> 6;
  const int lr = l & 15, lq = l >> 4;

  int lin = blockIdx.x;                       // 1152 blocks
  int swz = (lin & 7) * 144 + (lin >> 3);     // XCD-aware bijective
  int xt = swz % 6;
  int rest = swz / 6;                         // 0..191
  int yp = rest % 96, b = rest / 96;
  int Y = yp * 2, x0 = xt * 32;
  int yrow = Y + (wv >> 1);                   // this wave's output row
  int xpix = x0 + (wv & 1) * 16 + lr;         // this lane's pixel

  const int wy = Y - 2, wx = x0 - 3;          // window origin (image coords)
  const unsigned short* gpb = gp + (size_t)b * 8 * HW_ * 8;

  // ---- stage window: 2048 slots x 16B, all waves FULLY ACTIVE each iter
  #pragma unroll
  for (int i = 0; i < 8; ++i) {
    int p  = t + i * 256;                     // 0..2047
    int g  = min(p / 241, 7);
    int rc = p - g * 241;
    int rcc = min(rc, 239);                   // pad slots -> clamped source
    int r  = rcc / 40;
    int c  = rcc - r * 40;
    int yr = min(max(wy + r, 0), HH - 1);
    int xc = min(max(wx + c, 0), WW - 1);
    const unsigned short* src = gpb + ((size_t)g * HW_ + (size_t)yr * WW + xc) * 8;
    __builtin_amdgcn_global_load_lds((GLB*)src,
                                     (LDS*)(win + (size_t)p * 8), 16, 0, 0);
  }

  // ---- preload offsets, packed (dy | dx<<16) per (group-pair, tap)
  unsigned dd[2][9];
  #pragma unroll
  for (int gi = 0; gi < 2; ++gi) {
    int g = lq + gi * 4;
    const unsigned short* op = off + ((size_t)(b * 144 + g * 18) * HH + yrow) * WW + xpix;
    #pragma unroll
    for (int k = 0; k < 9; ++k) {
      unsigned dyv = op[(size_t)(2 * k) * HW_];
      unsigned dxv = op[(size_t)(2 * k + 1) * HW_];
      dd[gi][k] = dyv | (dxv << 16);
    }
  }

  __syncthreads();                            // window ready (single barrier)

  f32x4 acc[4];
  #pragma unroll
  for (int f = 0; f < 4; ++f) acc[f] = f32x4{0.f, 0.f, 0.f, 0.f};

  #pragma unroll
  for (int k = 0; k < 9; ++k) {
    const int ky = k / 3, kx = k % 3;
    bf16x8 pf0, pf1;
    #pragma unroll
    for (int gi = 0; gi < 2; ++gi) {
      int g = lq + gi * 4;
      float dyv = bf2f((unsigned short)(dd[gi][k] & 0xffffu));
      float dxv = bf2f((unsigned short)(dd[gi][k] >> 16));
      float py = (float)(yrow - 1 + ky) + dyv;
      float px = (float)(xpix - 1 + kx) + dxv;
      float fy0 = floorf(py), fx0 = floorf(px);
      float wy1 = py - fy0, wx1 = px - fx0;
      float wy0 = 1.f - wy1, wx0 = 1.f - wx1;
      bool vy0 = (fy0 >= 0.f)  && (fy0 <= 191.f);
      bool vy1 = (fy0 >= -1.f) && (fy0 <= 190.f);
      bool vx0 = (fx0 >= 0.f)  && (fx0 <= 191.f);
      bool vx1 = (fx0 >= -1.f) && (fx0 <= 190.f);
      float c00 = (vy0 && vx0) ? wy0 * wx0 : 0.f;
      float c01 = (vy0 && vx1) ? wy0 * wx1 : 0.f;
      float c10 = (vy1 && vx0) ? wy1 * wx0 : 0.f;
      float c11 = (vy1 && vx1) ? wy1 * wx1 : 0.f;
      int iy0 = (int)fminf(fmaxf(fy0, 0.f), 191.f);
      int iy1 = (int)fminf(fmaxf(fy0 + 1.f, 0.f), 191.f);
      int ix0 = (int)fminf(fmaxf(fx0, 0.f), 191.f);
      int ix1 = (int)fminf(fmaxf(fx0 + 1.f, 0.f), 191.f);
      bool inw = (iy0 >= wy) && (iy1 <= wy + 5) && (ix0 >= wx) && (ix1 <= wx + 39);
      int ry0 = min(max(iy0 - wy, 0), 5), ry1 = min(max(iy1 - wy, 0), 5);
      int rx0 = min(max(ix0 - wx, 0), 39), rx1 = min(max(ix1 - wx, 0), 39);
      const unsigned short* wg = win + (size_t)g * (241 * 8);
      bf16x8 v00 = *(const bf16x8*)(wg + ((size_t)ry0 * 40 + rx0) * 8);
      bf16x8 v01 = *(const bf16x8*)(wg + ((size_t)ry0 * 40 + rx1) * 8);
      bf16x8 v10 = *(const bf16x8*)(wg + ((size_t)ry1 * 40 + rx0) * 8);
      bf16x8 v11 = *(const bf16x8*)(wg + ((size_t)ry1 * 40 + rx1) * 8);
      if (!__all((int)inw)) {                 // rare: exact global fallback
        if (!inw) {
          const unsigned short* bb = gpb + (size_t)g * HW_ * 8;
          v00 = *(const bf16x8*)(bb + ((size_t)iy0 * WW + ix0) * 8);
          v01 = *(const bf16x8*)(bb + ((size_t)iy0 * WW + ix1) * 8);
          v10 = *(const bf16x8*)(bb + ((size_t)iy1 * WW + ix0) * 8);
          v11 = *(const bf16x8*)(bb + ((size_t)iy1 * WW + ix1) * 8);
        }
      }
      bf16x8 sv;
      #pragma unroll
      for (int j = 0; j < 8; ++j) {
        float s = bf2f((unsigned short)v00[j]) * c00
                + bf2f((unsigned short)v01[j]) * c01
                + bf2f((unsigned short)v10[j]) * c10
                + bf2f((unsigned short)v11[j]) * c11;
        sv[j] = (short)f2bf(s);
      }
      if (gi == 0) pf0 = sv; else pf1 = sv;
    }
    #pragma unroll
    for (int f = 0; f < 4; ++f) {
      bf16x8 wf = *(const bf16x8*)&wD[((size_t)k * 64 + f * 16 + lr) * 64 + lq * 8];
      acc[f] = __builtin_amdgcn_mfma_f32_16x16x32_bf16(wf, pf0, acc[f], 0, 0, 0);
    }
    #pragma unroll
    for (int f = 0; f < 4; ++f) {
      bf16x8 wf = *(const bf16x8*)&wD[((size_t)k * 64 + f * 16 + lr) * 64 + 32 + lq * 8];
      acc[f] = __builtin_amdgcn_mfma_f32_16x16x32_bf16(wf, pf1, acc[f], 0, 0, 0);
    }
  }

  // epilogue: NHWC bf16 into concat channels [0,64). C: col=pixel=lr, row=lq*4+j
  unsigned short* outc = concatT + (size_t)b * HP * WPAD * 128;
  #pragma unroll
  for (int f = 0; f < 4; ++f) {
    int co = f * 16 + lq * 4;
    f32x4 bv = *(const f32x4*)&bias[co];
    s16x4 s;
    #pragma unroll
    for (int j = 0; j < 4; ++j) s[j] = (short)f2bf(acc[f][j] + bv[j]);
    *(s16x4*)&outc[((size_t)(yrow + 1) * WPAD + xpix + 1) * 128 + co] = s;
  }
}

// ---------------------------------------------------------------------------
extern "C" void kernel_launch(void* const* d_in, const int* in_sizes, int n_in,
                              void* d_out, int out_size, void* d_ws, size_t ws_size,
                              hipStream_t stream)
{
  const float* prev  = (const float*)d_in[0];
  const float* offin = (const float*)d_in[1];
  const float* w_off = (const float*)d_in[2];
  const float* b_off = (const float*)d_in[3];
  const float* w_dcn = (const float*)d_in[4];
  const float* b_dcn = (const float*)d_in[5];
  const float* w_r1  = (const float*)d_in[6];
  const float* b_r1  = (const float*)d_in[7];
  const float* w_r2  = (const float*)d_in[8];
  const float* b_r2  = (const float*)d_in[9];
  float* out = (float*)d_out;

  char* p = (char*)d_ws;
  unsigned short* offs_t   = (unsigned short*)p; p += (size_t)B_ * HP * WPAD * 64 * 2;   //  9.93 MB
  unsigned short* concat_t = (unsigned short*)p; p += (size_t)B_ * HP * WPAD * 128 * 2;  // 19.87 MB
  unsigned short* r1_t     = (unsigned short*)p; p += (size_t)B_ * HP * WPAD * 64 * 2;   //  9.93 MB
  unsigned short* offf     = (unsigned short*)p; p += (size_t)B_ * 144 * HW_ * 2;        // 21.23 MB
  unsigned short* wOffB    = (unsigned short*)p; p += 144 * 576 * 2;
  unsigned short* wDcnB    = (unsigned short*)p; p += 64 * 576 * 2;
  unsigned short* wR1B     = (unsigned short*)p; p += 64 * 1152 * 2;
  unsigned short* wR2B     = (unsigned short*)p; p += 64 * 576 * 2;                      // total ~61.4 MB
  // gp (group-planar prev, 9.44 MB) aliases offs_t (9.93 MB): offs_t is dead
  // after K1, and to_gp runs after K1 on the same stream.
  unsigned short* gp = offs_t;

  // Zero padded NHWC buffers (contiguous) so pad borders are 0.
  hipMemsetAsync(offs_t, 0, (size_t)B_ * HP * WPAD * (64 + 128 + 64) * 2, stream);

  wxform<<<900, 256, 0, stream>>>(w_off, w_dcn, w_r1, w_r2, wOffB, wDcnB, wR1B, wR2B);
  to_nhwc<64,  true ><<<dim3(12, 384), 256, 0, stream>>>(offin, offs_t, 0);
  to_nhwc<128, true ><<<dim3(12, 384), 256, 0, stream>>>(prev,  concat_t, 64);

  // K1: offset conv (64 -> 144), bf16 NCHW out.
  conv_mfma<64, 144, 9, false, 0, true><<<dim3(3, 384), 256, 0, stream>>>(
      offs_t, wOffB, b_off, nullptr, offf);

  // prev -> group-planar (overwrites offs_t region; K1 is done with it)
  to_gp<<<2304, 256, 0, stream>>>(prev, gp);

  // K2: deformable conv -> concat_t channels [0,64). LDS-window, 2x32 tile.
  deform_mfma<<<1152, 256, 0, stream>>>(gp, offf, wDcnB, b_dcn, concat_t);

  // K3: r1 = leaky(conv(concat)) (128 -> 64), NHWC padded out.
  conv_mfma<128, 64, 4, true, 1, false><<<dim3(3, 384), 256, 0, stream>>>(
      concat_t, wR1B, b_r1, nullptr, r1_t);

  // K4: out = aligned + leaky(conv(r1)) (64 -> 64), f32 NCHW out.
  conv_mfma<64, 64, 4, true, 2, true><<<dim3(3, 384), 256, 0, stream>>>(
      r1_t, wR2B, b_r2, concat_t, out);
}

// Round 12
// 152.697 us; speedup vs baseline: 1.2070x; 1.1410x over previous
//
#include <hip/hip_runtime.h>
#include <hip/hip_bf16.h>
#include <cstdint>
#include <cstddef>

constexpr int B_ = 2;
constexpr int HH = 192, WW = 192, HW_ = HH * WW;
constexpr int HP = 194, WPAD = 200;   // padded dims

typedef short bf16x8 __attribute__((ext_vector_type(8)));
typedef short s16x4  __attribute__((ext_vector_type(4)));
typedef float f32x4  __attribute__((ext_vector_type(4)));
typedef unsigned int u32x4 __attribute__((ext_vector_type(4)));

typedef __attribute__((address_space(1))) const void GLB;
typedef __attribute__((address_space(3))) void LDS;

__device__ __forceinline__ float bf2f(unsigned short h) {
  union { unsigned u; float f; } v; v.u = (unsigned)h << 16; return v.f;
}
__device__ __forceinline__ unsigned short f2bf(float f) {
  union { float f; unsigned u; } v; v.f = f;
  unsigned u = v.u;
  u += 0x7fffu + ((u >> 16) & 1u);
  return (unsigned short)(u >> 16);
}
__device__ __forceinline__ float leaky(float v) { return fmaxf(v, 0.1f * v); }

// ---------------------------------------------------------------------------
// Border zeroing: pad frames of offs_t (64ch), concat_t (128ch), r1_t (64ch).
// Interiors are fully rewritten every call; borders only here (2 MB total).
// ---------------------------------------------------------------------------
__global__ __launch_bounds__(256) void borderzero(unsigned short* __restrict__ offs_t,
                                                  unsigned short* __restrict__ concat_t,
                                                  unsigned short* __restrict__ r1_t)
{
  int tid = blockIdx.x * 256 + threadIdx.x;     // covers 2*194*200 = 77600
  if (tid >= B_ * HP * WPAD) return;
  int x = tid % WPAD, y = (tid / WPAD) % HP, b = tid / (HP * WPAD);
  bool border = (y == 0) || (y >= 193) || (x == 0) || (x >= 193);
  if (!border) return;
  size_t px = (size_t)(b * HP + y) * WPAD + x;
  u32x4 z4 = {0u, 0u, 0u, 0u};
  u32x4* p0 = (u32x4*)(offs_t   + px * 64);     // 8 x 16B
  u32x4* p1 = (u32x4*)(concat_t + px * 128);    // 16 x 16B
  u32x4* p2 = (u32x4*)(r1_t     + px * 64);     // 8 x 16B
  #pragma unroll
  for (int i = 0; i < 8; ++i)  p0[i] = z4;
  #pragma unroll
  for (int i = 0; i < 16; ++i) p1[i] = z4;
  #pragma unroll
  for (int i = 0; i < 8; ++i)  p2[i] = z4;
}

// ---------------------------------------------------------------------------
// NCHW f32 -> NHWC bf16 (padded interior of [HP][WPAD]).  (offsets input)
// ---------------------------------------------------------------------------
template<int DSTC>
__global__ __launch_bounds__(256) void to_nhwc(const float* __restrict__ src,
                                               unsigned short* __restrict__ dst,
                                               int coff)
{
  __shared__ float tile[16][65];
  int t = threadIdx.x;
  int xc = blockIdx.x * 16;
  int y = blockIdx.y % HH, b = blockIdx.y / HH;
  #pragma unroll
  for (int cp = 0; cp < 4; ++cp) {
    int c = cp * 16 + (t >> 4);
    tile[t & 15][c] = src[((size_t)(b * 64 + c) * HH + y) * WW + xc + (t & 15)];
  }
  __syncthreads();
  int x = t >> 4, c4 = (t & 15) * 4;
  s16x4 s;
  #pragma unroll
  for (int j = 0; j < 4; ++j) s[j] = (short)f2bf(tile[x][c4 + j]);
  *(s16x4*)&dst[((size_t)(b * HP + y + 1) * WPAD + xc + x + 1) * DSTC + coff + c4] = s;
}

// ---------------------------------------------------------------------------
// prev NCHW f32 -> BOTH concat_t ch[64,128) (padded NHWC) AND group-planar gp.
// Fuses the old to_nhwc<128> + to_gp: prev read once, one dispatch fewer.
// ---------------------------------------------------------------------------
__global__ __launch_bounds__(256) void prep_prev(const float* __restrict__ src,
                                                 unsigned short* __restrict__ concatT,
                                                 unsigned short* __restrict__ gp)
{
  __shared__ float tile[16][65];
  int t = threadIdx.x;
  int xc = blockIdx.x * 16;
  int y = blockIdx.y % HH, b = blockIdx.y / HH;
  #pragma unroll
  for (int cp = 0; cp < 4; ++cp) {
    int c = cp * 16 + (t >> 4);
    tile[t & 15][c] = src[((size_t)(b * 64 + c) * HH + y) * WW + xc + (t & 15)];
  }
  __syncthreads();
  int x = t >> 4, c4 = (t & 15) * 4;
  s16x4 s;
  #pragma unroll
  for (int j = 0; j < 4; ++j) s[j] = (short)f2bf(tile[x][c4 + j]);
  *(s16x4*)&concatT[((size_t)(b * HP + y + 1) * WPAD + xc + x + 1) * 128 + 64 + c4] = s;
  int g = c4 >> 3, co = c4 & 7;
  *(s16x4*)&gp[((size_t)(b * 8 + g) * HW_ + (size_t)y * WW + xc + x) * 8 + co] = s;
}

// ---------------------------------------------------------------------------
// Weight transform: (O, CI, 3, 3) f32 -> tap-major [k][o][ci] bf16.
// K1/K3/K4 images get the LDS XOR bank-swizzle; deform (w_dcn) stays plain.
// ---------------------------------------------------------------------------
__global__ __launch_bounds__(256) void wxform(
    const float* __restrict__ w_off, const float* __restrict__ w_dcn,
    const float* __restrict__ w_r1,  const float* __restrict__ w_r2,
    unsigned short* __restrict__ wOffB, unsigned short* __restrict__ wDcnB,
    unsigned short* __restrict__ wR1B,  unsigned short* __restrict__ wR2B)
{
  int tid = blockIdx.x * 256 + threadIdx.x;   // 230400 total
  const float* src; unsigned short* dst; int CI, CO, idx; bool dosw = true;
  if (tid < 82944)            { src = w_off; dst = wOffB; CI = 64;  CO = 144; idx = tid; }
  else if (tid < 119808)      { src = w_dcn; dst = wDcnB; CI = 64;  CO = 64;  idx = tid - 82944; dosw = false; }
  else if (tid < 193536)      { src = w_r1;  dst = wR1B;  CI = 128; CO = 64;  idx = tid - 119808; }
  else                        { src = w_r2;  dst = wR2B;  CI = 64;  CO = 64;  idx = tid - 193536; }
  int ci = idx % CI;
  int k  = (idx / CI) % 9;
  int o  = idx / (CI * 9);
  int pci = dosw ? (((((ci >> 3) ^ (o & 7))) << 3) | (ci & 7)) : ci;
  dst[((size_t)k * CO + o) * CI + pci] = f2bf(src[((size_t)o * CI + ci) * 9 + k]);
}

// ---------------------------------------------------------------------------
// MFMA implicit-GEMM 3x3 conv. Pixels staged once in LDS; per-tap weight
// SLICE (NF*16 couts starting at blockIdx.z*NF*16) staged via global_load_lds.
// All weight-staging trip counts are multiples of 128 (full waves only).
// OUTMODE 0: bf16 NCHW (K1) | 1: bf16 NHWC padded (K3) | 2: f32 NCHW + resid (K4)
// ---------------------------------------------------------------------------
template<int CIN, int COUT, int NF, bool LEAKY_, int OUTMODE, bool DBUF>
__global__ __launch_bounds__(256, 4) void conv_mfma(
    const unsigned short* __restrict__ inT,   // [b][HP][WPAD][CIN] bf16
    const unsigned short* __restrict__ wS,    // [9][COUT][CIN] bf16, swizzled image
    const float* __restrict__ bias,
    const unsigned short* __restrict__ resid,
    void* __restrict__ outp)
{
  constexpr int CPP  = CIN / 8;          // 16B chunks per pixel
  constexpr int TPX  = 72;
  constexpr int NCH  = TPX * CPP;        // chunks per staged row
  constexpr int RPR  = NCH / 64;         // wave-regions per row
  constexpr int NREG = 3 * RPR;
  constexpr int WSZ  = NF * 16 * CIN;    // weight elems per tap slice
  constexpr int WCH  = WSZ / 8;          // 16B chunks per tap slice (mult of 128)
  static_assert(WCH % 128 == 0, "staging must use full waves");
  __shared__ __align__(16) unsigned short tile[3 * TPX * CIN];
  __shared__ __align__(16) unsigned short wlds[(DBUF ? 2 : 1) * WSZ];

  const int t = threadIdx.x;
  const int l = t & 63, wv = t >> 6;
  const int lr = l & 15, lq = l >> 4, lk = lq * 8;

  // XCD-aware bijective swizzle over the spatial grid (1152 % 8 == 0)
  constexpr int NWG = 3 * 384;
  int lin = blockIdx.x + 3 * blockIdx.y;
  int swz = (lin & 7) * (NWG / 8) + (lin >> 3);
  int xq = swz % 3, yy = swz / 3;
  int y = yy % HH, b = yy / HH;
  int x0 = xq * 64;
  const int co0 = blockIdx.z * (NF * 16);   // cout slice origin (mult of 16)

  // ---- stage 3 pixel rows (72 px each, swizzled) + weight tap-0 slice
  {
    const unsigned short* base = inT + ((size_t)(b * HP + y) * WPAD + x0) * CIN;
    for (int r = wv; r < NREG; r += 4) {
      int row = r / RPR;
      int rr  = r % RPR;
      int d   = rr * 64 + l;
      int p   = d / CPP;
      int cj  = d % CPP;
      int sc  = p * CPP + (cj ^ (p & (CPP - 1)));
      const unsigned short* src = base + (size_t)row * WPAD * CIN + (size_t)sc * 8;
      unsigned short* dst = &tile[(size_t)(row * NCH + rr * 64) * 8];
      __builtin_amdgcn_global_load_lds((GLB*)src, (LDS*)dst, 16, 0, 0);
    }
  }
  {
    const unsigned short* srcb = wS + (size_t)co0 * CIN;   // tap 0 slice
    for (int r = t; r < WCH; r += 256)
      __builtin_amdgcn_global_load_lds((GLB*)(srcb + (size_t)r * 8),
                                       (LDS*)(&wlds[(size_t)r * 8]), 16, 0, 0);
  }
  __syncthreads();

  f32x4 acc[NF];
  #pragma unroll
  for (int f = 0; f < NF; ++f) acc[f] = f32x4{0.f, 0.f, 0.f, 0.f};

  #pragma unroll
  for (int k = 0; k < 9; ++k) {
    const int ky = k / 3, kx = k % 3;
    if (DBUF && k < 8) {
      const unsigned short* srcb = wS + (size_t)(k + 1) * COUT * CIN + (size_t)co0 * CIN;
      unsigned short* db = &wlds[(size_t)((k + 1) & 1) * WSZ];
      for (int r = t; r < WCH; r += 256)
        __builtin_amdgcn_global_load_lds((GLB*)(srcb + (size_t)r * 8),
                                         (LDS*)(db + (size_t)r * 8), 16, 0, 0);
    }
    // ---- compute tap k
    {
      const unsigned short* wb = &wlds[DBUF ? (size_t)(k & 1) * WSZ : 0];
      const int px = wv * 16 + lr + kx;
      #pragma unroll
      for (int c = 0; c < CIN; c += 32) {
        int cj = (c + lk) >> 3;
        bf16x8 pf = *(const bf16x8*)
            &tile[(size_t)(ky * NCH + px * CPP + (cj ^ (px & (CPP - 1)))) * 8];
        #pragma unroll
        for (int f = 0; f < NF; ++f) {
          int co = f * 16 + lr;             // local row; (co0+co)&7 == co&7
          bf16x8 wf = *(const bf16x8*)&wb[(size_t)co * CIN + ((cj ^ (co & 7)) << 3)];
          if (OUTMODE == 0)
            acc[f] = __builtin_amdgcn_mfma_f32_16x16x32_bf16(pf, wf, acc[f], 0, 0, 0);
          else
            acc[f] = __builtin_amdgcn_mfma_f32_16x16x32_bf16(wf, pf, acc[f], 0, 0, 0);
        }
      }
    }
    if (DBUF) {
      __syncthreads();
    } else if (k < 8) {
      __syncthreads();                       // all reads of wlds done
      const unsigned short* srcb = wS + (size_t)(k + 1) * COUT * CIN + (size_t)co0 * CIN;
      for (int r = t; r < WCH; r += 256)
        __builtin_amdgcn_global_load_lds((GLB*)(srcb + (size_t)r * 8),
                                         (LDS*)(&wlds[(size_t)r * 8]), 16, 0, 0);
      __syncthreads();                       // staging complete
    }
  }

  if (OUTMODE == 0) {
    int xs = x0 + wv * 16 + lq * 4;
    #pragma unroll
    for (int f = 0; f < NF; ++f) {
      int coG = co0 + f * 16 + lr;
      float bv = bias[coG];
      s16x4 s;
      #pragma unroll
      for (int j = 0; j < 4; ++j) {
        float v = acc[f][j] + bv;
        if (LEAKY_) v = leaky(v);
        s[j] = (short)f2bf(v);
      }
      *(s16x4*)((unsigned short*)outp + ((size_t)(b * COUT + coG) * HH + y) * WW + xs) = s;
    }
  } else if (OUTMODE == 1) {
    int x = x0 + wv * 16 + lr;
    #pragma unroll
    for (int f = 0; f < NF; ++f) {
      int co = f * 16 + lq * 4;
      f32x4 bv = *(const f32x4*)&bias[co];
      s16x4 s;
      #pragma unroll
      for (int j = 0; j < 4; ++j) {
        float v = acc[f][j] + bv[j];
        if (LEAKY_) v = leaky(v);
        s[j] = (short)f2bf(v);
      }
      *(s16x4*)((unsigned short*)outp + ((size_t)(b * HP + y + 1) * WPAD + x + 1) * 64 + co) = s;
    }
  } else {
    int x = x0 + wv * 16 + lr;
    const unsigned short* rbase = resid + ((size_t)(b * HP + y + 1) * WPAD + x + 1) * 128;
    float* ob = (float*)outp + (size_t)b * 64 * HW_ + (size_t)y * WW + x;
    #pragma unroll
    for (int f = 0; f < NF; ++f) {
      int cob = f * 16 + lq * 4;
      f32x4 bv = *(const f32x4*)&bias[cob];
      s16x4 rv = *(const s16x4*)&rbase[cob];
      #pragma unroll
      for (int j = 0; j < 4; ++j) {
        float v = acc[f][j] + bv[j];
        if (LEAKY_) v = leaky(v);
        v += bf2f((unsigned short)rv[j]);
        ob[(size_t)(cob + j) * HW_] = v;
      }
    }
  }
}

// ---------------------------------------------------------------------------
// Deformable conv (R11-proven: passes both validations). LDS-window, 2x32
// tile, 2048-slot full-wave staging, group stride 241 slots.
// ---------------------------------------------------------------------------
__global__ __launch_bounds__(256, 4) void deform_mfma(
    const unsigned short* __restrict__ gp,    // [b][8][192][192][8] bf16
    const unsigned short* __restrict__ off,   // [b][144][192][192] bf16
    const unsigned short* __restrict__ wD,    // [9][64][64] bf16 plain
    const float* __restrict__ bias,
    unsigned short* __restrict__ concatT)     // [b][HP][WPAD][128], writes ch0-63
{
  __shared__ __align__(16) unsigned short win[2048 * 8];   // 32768 B
  const int t = threadIdx.x;
  const int l = t & 63, wv = t >> 6;
  const int lr = l & 15, lq = l >> 4;

  int lin = blockIdx.x;                       // 1152 blocks
  int swz = (lin & 7) * 144 + (lin >> 3);     // XCD-aware bijective
  int xt = swz % 6;
  int rest = swz / 6;                         // 0..191
  int yp = rest % 96, b = rest / 96;
  int Y = yp * 2, x0 = xt * 32;
  int yrow = Y + (wv >> 1);                   // this wave's output row
  int xpix = x0 + (wv & 1) * 16 + lr;         // this lane's pixel

  const int wy = Y - 2, wx = x0 - 3;          // window origin (image coords)
  const unsigned short* gpb = gp + (size_t)b * 8 * HW_ * 8;

  // ---- stage window: 2048 slots x 16B, all waves FULLY ACTIVE each iter
  #pragma unroll
  for (int i = 0; i < 8; ++i) {
    int p  = t + i * 256;                     // 0..2047
    int g  = min(p / 241, 7);
    int rc = p - g * 241;
    int rcc = min(rc, 239);                   // pad slots -> clamped source
    int r  = rcc / 40;
    int c  = rcc - r * 40;
    int yr = min(max(wy + r, 0), HH - 1);
    int xc = min(max(wx + c, 0), WW - 1);
    const unsigned short* src = gpb + ((size_t)g * HW_ + (size_t)yr * WW + xc) * 8;
    __builtin_amdgcn_global_load_lds((GLB*)src,
                                     (LDS*)(win + (size_t)p * 8), 16, 0, 0);
  }

  // ---- preload offsets, packed (dy | dx<<16) per (group-pair, tap)
  unsigned dd[2][9];
  #pragma unroll
  for (int gi = 0; gi < 2; ++gi) {
    int g = lq + gi * 4;
    const unsigned short* op = off + ((size_t)(b * 144 + g * 18) * HH + yrow) * WW + xpix;
    #pragma unroll
    for (int k = 0; k < 9; ++k) {
      unsigned dyv = op[(size_t)(2 * k) * HW_];
      unsigned dxv = op[(size_t)(2 * k + 1) * HW_];
      dd[gi][k] = dyv | (dxv << 16);
    }
  }

  __syncthreads();                            // window ready (single barrier)

  f32x4 acc[4];
  #pragma unroll
  for (int f = 0; f < 4; ++f) acc[f] = f32x4{0.f, 0.f, 0.f, 0.f};

  #pragma unroll
  for (int k = 0; k < 9; ++k) {
    const int ky = k / 3, kx = k % 3;
    bf16x8 pf0, pf1;
    #pragma unroll
    for (int gi = 0; gi < 2; ++gi) {
      int g = lq + gi * 4;
      float dyv = bf2f((unsigned short)(dd[gi][k] & 0xffffu));
      float dxv = bf2f((unsigned short)(dd[gi][k] >> 16));
      float py = (float)(yrow - 1 + ky) + dyv;
      float px = (float)(xpix - 1 + kx) + dxv;
      float fy0 = floorf(py), fx0 = floorf(px);
      float wy1 = py - fy0, wx1 = px - fx0;
      float wy0 = 1.f - wy1, wx0 = 1.f - wx1;
      bool vy0 = (fy0 >= 0.f)  && (fy0 <= 191.f);
      bool vy1 = (fy0 >= -1.f) && (fy0 <= 190.f);
      bool vx0 = (fx0 >= 0.f)  && (fx0 <= 191.f);
      bool vx1 = (fx0 >= -1.f) && (fx0 <= 190.f);
      float c00 = (vy0 && vx0) ? wy0 * wx0 : 0.f;
      float c01 = (vy0 && vx1) ? wy0 * wx1 : 0.f;
      float c10 = (vy1 && vx0) ? wy1 * wx0 : 0.f;
      float c11 = (vy1 && vx1) ? wy1 * wx1 : 0.f;
      int iy0 = (int)fminf(fmaxf(fy0, 0.f), 191.f);
      int iy1 = (int)fminf(fmaxf(fy0 + 1.f, 0.f), 191.f);
      int ix0 = (int)fminf(fmaxf(fx0, 0.f), 191.f);
      int ix1 = (int)fminf(fmaxf(fx0 + 1.f, 0.f), 191.f);
      bool inw = (iy0 >= wy) && (iy1 <= wy + 5) && (ix0 >= wx) && (ix1 <= wx + 39);
      int ry0 = min(max(iy0 - wy, 0), 5), ry1 = min(max(iy1 - wy, 0), 5);
      int rx0 = min(max(ix0 - wx, 0), 39), rx1 = min(max(ix1 - wx, 0), 39);
      const unsigned short* wg = win + (size_t)g * (241 * 8);
      bf16x8 v00 = *(const bf16x8*)(wg + ((size_t)ry0 * 40 + rx0) * 8);
      bf16x8 v01 = *(const bf16x8*)(wg + ((size_t)ry0 * 40 + rx1) * 8);
      bf16x8 v10 = *(const bf16x8*)(wg + ((size_t)ry1 * 40 + rx0) * 8);
      bf16x8 v11 = *(const bf16x8*)(wg + ((size_t)ry1 * 40 + rx1) * 8);
      if (!__all((int)inw)) {                 // rare: exact global fallback
        if (!inw) {
          const unsigned short* bb = gpb + (size_t)g * HW_ * 8;
          v00 = *(const bf16x8*)(bb + ((size_t)iy0 * WW + ix0) * 8);
          v01 = *(const bf16x8*)(bb + ((size_t)iy0 * WW + ix1) * 8);
          v10 = *(const bf16x8*)(bb + ((size_t)iy1 * WW + ix0) * 8);
          v11 = *(const bf16x8*)(bb + ((size_t)iy1 * WW + ix1) * 8);
        }
      }
      bf16x8 sv;
      #pragma unroll
      for (int j = 0; j < 8; ++j) {
        float s = bf2f((unsigned short)v00[j]) * c00
                + bf2f((unsigned short)v01[j]) * c01
                + bf2f((unsigned short)v10[j]) * c10
                + bf2f((unsigned short)v11[j]) * c11;
        sv[j] = (short)f2bf(s);
      }
      if (gi == 0) pf0 = sv; else pf1 = sv;
    }
    #pragma unroll
    for (int f = 0; f < 4; ++f) {
      bf16x8 wf = *(const bf16x8*)&wD[((size_t)k * 64 + f * 16 + lr) * 64 + lq * 8];
      acc[f] = __builtin_amdgcn_mfma_f32_16x16x32_bf16(wf, pf0, acc[f], 0, 0, 0);
    }
    #pragma unroll
    for (int f = 0; f < 4; ++f) {
      bf16x8 wf = *(const bf16x8*)&wD[((size_t)k * 64 + f * 16 + lr) * 64 + 32 + lq * 8];
      acc[f] = __builtin_amdgcn_mfma_f32_16x16x32_bf16(wf, pf1, acc[f], 0, 0, 0);
    }
  }

  // epilogue: NHWC bf16 into concat channels [0,64)
  unsigned short* outc = concatT + (size_t)b * HP * WPAD * 128;
  #pragma unroll
  for (int f = 0; f < 4; ++f) {
    int co = f * 16 + lq * 4;
    f32x4 bv = *(const f32x4*)&bias[co];
    s16x4 s;
    #pragma unroll
    for (int j = 0; j < 4; ++j) s[j] = (short)f2bf(acc[f][j] + bv[j]);
    *(s16x4*)&outc[((size_t)(yrow + 1) * WPAD + xpix + 1) * 128 + co] = s;
  }
}

// ---------------------------------------------------------------------------
extern "C" void kernel_launch(void* const* d_in, const int* in_sizes, int n_in,
                              void* d_out, int out_size, void* d_ws, size_t ws_size,
                              hipStream_t stream)
{
  const float* prev  = (const float*)d_in[0];
  const float* offin = (const float*)d_in[1];
  const float* w_off = (const float*)d_in[2];
  const float* b_off = (const float*)d_in[3];
  const float* w_dcn = (const float*)d_in[4];
  const float* b_dcn = (const float*)d_in[5];
  const float* w_r1  = (const float*)d_in[6];
  const float* b_r1  = (const float*)d_in[7];
  const float* w_r2  = (const float*)d_in[8];
  const float* b_r2  = (const float*)d_in[9];
  float* out = (float*)d_out;

  char* p = (char*)d_ws;
  unsigned short* offs_t   = (unsigned short*)p; p += (size_t)B_ * HP * WPAD * 64 * 2;   //  9.93 MB
  unsigned short* concat_t = (unsigned short*)p; p += (size_t)B_ * HP * WPAD * 128 * 2;  // 19.87 MB
  unsigned short* r1_t     = (unsigned short*)p; p += (size_t)B_ * HP * WPAD * 64 * 2;   //  9.93 MB
  unsigned short* offf     = (unsigned short*)p; p += (size_t)B_ * 144 * HW_ * 2;        // 21.23 MB
  unsigned short* wOffB    = (unsigned short*)p; p += 144 * 576 * 2;
  unsigned short* wDcnB    = (unsigned short*)p; p += 64 * 576 * 2;
  unsigned short* wR1B     = (unsigned short*)p; p += 64 * 1152 * 2;
  unsigned short* wR2B     = (unsigned short*)p; p += 64 * 576 * 2;                      // total ~61.4 MB
  // gp aliases offs_t: offs_t is dead after K1; prep_prev runs after K1.
  unsigned short* gp = offs_t;

  // Border zeroing (replaces the 39.7 MB memset; interiors rewritten per call)
  borderzero<<<(B_ * HP * WPAD + 255) / 256, 256, 0, stream>>>(offs_t, concat_t, r1_t);

  wxform<<<900, 256, 0, stream>>>(w_off, w_dcn, w_r1, w_r2, wOffB, wDcnB, wR1B, wR2B);
  to_nhwc<64><<<dim3(12, 384), 256, 0, stream>>>(offin, offs_t, 0);

  // K1: offset conv (64 -> 144), cout-split x3 (grid 3456 = 13.5 blocks/CU).
  conv_mfma<64, 144, 3, false, 0, true><<<dim3(3, 384, 3), 256, 0, stream>>>(
      offs_t, wOffB, b_off, nullptr, offf);

  // prev -> concat ch[64,128) + group-planar gp (fused; overwrites offs_t)
  prep_prev<<<dim3(12, 384), 256, 0, stream>>>(prev, concat_t, gp);

  // K2: deformable conv -> concat_t channels [0,64).
  deform_mfma<<<1152, 256, 0, stream>>>(gp, offf, wDcnB, b_dcn, concat_t);

  // K3: r1 = leaky(conv(concat)) (128 -> 64), NHWC padded out.
  conv_mfma<128, 64, 4, true, 1, false><<<dim3(3, 384, 1), 256, 0, stream>>>(
      concat_t, wR1B, b_r1, nullptr, r1_t);

  // K4: out = aligned + leaky(conv(r1)) (64 -> 64), f32 NCHW out.
  conv_mfma<64, 64, 4, true, 2, true><<<dim3(3, 384, 1), 256, 0, stream>>>(
      r1_t, wR2B, b_r2, concat_t, out);
}